// Round 4
// baseline (595.430 us; speedup 1.0000x reference)
//
#include <hip/hip_runtime.h>

// PairwiseRankingLoss: out = 2*sum(cost_a) + sum(cost_g)
//   cost_x[i,j] = relu(score_x[i,j] + 0.2 - diag_x[j]) * (i != j)
//   score_a = artist @ target_art^T ; score_g = genre @ genre^T (symmetric)
// N=4096, D=1024. fp32 in; bf16 MFMA (2% rel threshold).
// Round 4: 256x256 tile, BK=32 double-buffer in 64 KiB LDS -> 2 blocks/CU,
//          all 392 blocks co-resident (kills the 2-round dispatch tail);
//          inter-block overlap hides ds_read/stage behind the other block's
//          MFMA. Counted vmcnt(4), 2-way-free LDS swizzle, setprio cluster.

#define NROW 4096
#define DDIM 1024
#define MARGIN 0.2f
#define NT 16               // 4096 / 256 tiles per dim
#define NKT 32              // 1024 / 32 K-tiles
#define NBLK_ART 256        // 16*16 artist tiles
#define NBLK_GEN 136        // genre upper triangle incl. diagonal
#define NBLK (NBLK_ART + NBLK_GEN)   // 392 = 8*49

typedef __bf16 bf16x8 __attribute__((ext_vector_type(8)));
typedef float f32x4 __attribute__((ext_vector_type(4)));

__device__ __forceinline__ unsigned short f2bf(float f) {
    unsigned int u = __builtin_bit_cast(unsigned int, f);
    u += 0x7fffu + ((u >> 16) & 1u);   // RNE
    return (unsigned short)(u >> 16);
}

__device__ __forceinline__ void gload_lds16(const void* g, void* l) {
    __builtin_amdgcn_global_load_lds(
        (const __attribute__((address_space(1))) void*)g,
        (__attribute__((address_space(3))) void*)l,
        16, 0, 0);
}

// ---- fused fp32->bf16 convert + per-row diagonals --------------------------
__global__ __launch_bounds__(256)
void prep_kernel(const float4* __restrict__ art, const float4* __restrict__ tart,
                 const float4* __restrict__ gen,
                 ushort4* __restrict__ artB, ushort4* __restrict__ tartB,
                 ushort4* __restrict__ genB,
                 float* __restrict__ diagA, float* __restrict__ diagG) {
    const int row = blockIdx.x;
    const int t = threadIdx.x;                  // 256 = DDIM/4 chunks
    const size_t idx = (size_t)row * (DDIM / 4) + t;
    float4 va = art[idx], vt = tart[idx], vg = gen[idx];
    ushort4 o;
    o.x = f2bf(va.x); o.y = f2bf(va.y); o.z = f2bf(va.z); o.w = f2bf(va.w); artB[idx] = o;
    o.x = f2bf(vt.x); o.y = f2bf(vt.y); o.z = f2bf(vt.z); o.w = f2bf(vt.w); tartB[idx] = o;
    o.x = f2bf(vg.x); o.y = f2bf(vg.y); o.z = f2bf(vg.z); o.w = f2bf(vg.w); genB[idx] = o;
    float pa = va.x * vt.x + va.y * vt.y + va.z * vt.z + va.w * vt.w;
    float pg = vg.x * vg.x + vg.y * vg.y + vg.z * vg.z + vg.w * vg.w;
    for (int off = 32; off > 0; off >>= 1) {
        pa += __shfl_down(pa, off, 64);
        pg += __shfl_down(pg, off, 64);
    }
    __shared__ float sA[4], sG[4];
    if ((t & 63) == 0) { sA[t >> 6] = pa; sG[t >> 6] = pg; }
    __syncthreads();
    if (t == 0) {
        diagA[row] = sA[0] + sA[1] + sA[2] + sA[3];
        diagG[row] = sG[0] + sG[1] + sG[2] + sG[3];
    }
}

// ---- LDS geometry -----------------------------------------------------------
// Per buffer: A 256x32 bf16 (8192 ushort), B same. Two buffers: 32768 ushort
// = 64 KiB total -> 2 blocks/CU.
// Row r = 32 bf16 = 4 slots of 16B. Swizzle: LDS (r, s) holds global k-group
//   g = s ^ ((r>>1)&3).  Frag read (16 rows x 4 k-groups) -> every bank-phase
//   hit exactly 2x => 2-way, free (m136).

__device__ __forceinline__
void stage_tile(int t, const unsigned short* __restrict__ Ablk,
                const unsigned short* __restrict__ Bblk,
                unsigned short* sh, int tid) {
    const int p = t & 1;
    const int kt = t << 5;
    unsigned short* dA = sh + p * 8192;
    unsigned short* dB = sh + 16384 + p * 8192;
#pragma unroll
    for (int i = 0; i < 2; ++i) {
        const int q = i * 512 + tid;                    // 16B chunk 0..1023
        const int r = q >> 2;
        const int g = (q & 3) ^ ((r >> 1) & 3);         // inverse-swizzled src
        gload_lds16(Ablk + (size_t)r * DDIM + kt + g * 8, dA + q * 8);
    }
#pragma unroll
    for (int i = 0; i < 2; ++i) {
        const int q = i * 512 + tid;
        const int r = q >> 2;
        const int g = (q & 3) ^ ((r >> 1) & 3);
        gload_lds16(Bblk + (size_t)r * DDIM + kt + g * 8, dB + q * 8);
    }
}

__device__ __forceinline__
bf16x8 lds_frag(const unsigned short* base, int r, int g) {
    const int s = g ^ ((r >> 1) & 3);
    return *(const bf16x8*)&base[r * 32 + s * 8];
}

// ---- fused 256x256 GEMM + hinge + reduction ---------------------------------
__global__ __launch_bounds__(512, 4)
void hinge_gemm_kernel(const unsigned short* __restrict__ artB,
                       const unsigned short* __restrict__ tartB,
                       const unsigned short* __restrict__ genB,
                       const float* __restrict__ diagA,
                       const float* __restrict__ diagG,
                       float* __restrict__ partials) {
    __shared__ unsigned short sh[32768];   // 64 KiB

    // bijective XCD swizzle: 392 = 8 * 49
    const int bid = ((int)blockIdx.x & 7) * 49 + ((int)blockIdx.x >> 3);

    const unsigned short* A;
    const unsigned short* B;
    const float* dg;
    int tr, tc, mode;          // mode 0: single hinge + diag mask; 1: dual hinge
    float scale;
    if (bid < NBLK_ART) {
        A = artB; B = tartB; dg = diagA; scale = 2.0f;
        tr = bid >> 4; tc = bid & 15; mode = 0;
    } else {
        int u = bid - NBLK_ART;
        int r = 0;
        while (u >= NT - r) { u -= NT - r; ++r; }
        tr = r; tc = r + u;
        A = genB; B = genB; dg = diagG; scale = 1.0f;
        mode = (tr == tc) ? 0 : 1;
    }

    const int tid = threadIdx.x;
    const int w = tid >> 6;
    const int lane = tid & 63;
    const int waveM = w >> 2;        // 2 wave-rows (128 rows each)
    const int waveN = w & 3;         // 4 wave-cols (64 cols each)

    const unsigned short* Ablk = A + (size_t)tr * 256 * DDIM;
    const unsigned short* Bblk = B + (size_t)tc * 256 * DDIM;

    f32x4 acc[8][4];
#pragma unroll
    for (int m = 0; m < 8; ++m)
#pragma unroll
        for (int n = 0; n < 4; ++n)
            acc[m][n] = (f32x4){0.f, 0.f, 0.f, 0.f};

    // prologue: tiles 0,1 in flight (8 loads/thread)
    stage_tile(0, Ablk, Bblk, sh, tid);
    stage_tile(1, Ablk, Bblk, sh, tid);

#pragma unroll 2
    for (int t = 0; t < NKT; ++t) {
        const unsigned short* lA = sh + (t & 1) * 8192;
        const unsigned short* lB = sh + 16384 + (t & 1) * 8192;

        // tile t landed (leave tile t+1's 4 loads in flight)
        if (t < NKT - 1) asm volatile("s_waitcnt vmcnt(4)" ::: "memory");
        else             asm volatile("s_waitcnt vmcnt(0)" ::: "memory");
        __builtin_amdgcn_s_barrier();
        __builtin_amdgcn_sched_barrier(0);

        bf16x8 aF[8], bF[4];
        const int g = lane >> 4;
#pragma unroll
        for (int m = 0; m < 8; ++m)
            aF[m] = lds_frag(lA, waveM * 128 + m * 16 + (lane & 15), g);
#pragma unroll
        for (int n = 0; n < 4; ++n)
            bF[n] = lds_frag(lB, waveN * 64 + n * 16 + (lane & 15), g);

        // all my reads complete BEFORE the barrier => after it, buffer is
        // overwritable by any wave's stage of tile t+2.
        asm volatile("s_waitcnt lgkmcnt(0)" ::: "memory");
        __builtin_amdgcn_s_barrier();

        if (t + 2 < NKT) stage_tile(t + 2, Ablk, Bblk, sh, tid);

        __builtin_amdgcn_s_setprio(1);
#pragma unroll
        for (int m = 0; m < 8; ++m)
#pragma unroll
            for (int n = 0; n < 4; ++n)
                acc[m][n] = __builtin_amdgcn_mfma_f32_16x16x32_bf16(
                    aF[m], bF[n], acc[m][n], 0, 0, 0);
        __builtin_amdgcn_s_setprio(0);
    }

    // ---- epilogue: hinge + reduction ----
    // C/D layout: col = lane&15, row = (lane>>4)*4 + reg
    const int rowBase = tr * 256 + waveM * 128 + ((lane >> 4) << 2);
    const int colBase = tc * 256 + waveN * 64 + (lane & 15);
    float lsum = 0.0f;
    if (mode == 0) {
#pragma unroll
        for (int nf = 0; nf < 4; ++nf) {
            const int gcol = colBase + nf * 16;
            const float dc = MARGIN - dg[gcol];
#pragma unroll
            for (int mf = 0; mf < 8; ++mf) {
                const int grow0 = rowBase + mf * 16;
#pragma unroll
                for (int r = 0; r < 4; ++r) {
                    float v = fmaxf(acc[mf][nf][r] + dc, 0.0f);
                    if (grow0 + r == gcol) v = 0.0f;
                    lsum += v;
                }
            }
        }
    } else {
        // strictly-above-diagonal genre tile: v = g[i,j] = g[j,i] contributes
        // relu(v + c_j) [this tile] + relu(v + c_i) [mirror tile]
        float drow[8][4];
#pragma unroll
        for (int mf = 0; mf < 8; ++mf)
#pragma unroll
            for (int r = 0; r < 4; ++r)
                drow[mf][r] = MARGIN - dg[rowBase + mf * 16 + r];
#pragma unroll
        for (int nf = 0; nf < 4; ++nf) {
            const float dc = MARGIN - dg[colBase + nf * 16];
#pragma unroll
            for (int mf = 0; mf < 8; ++mf)
#pragma unroll
                for (int r = 0; r < 4; ++r) {
                    const float v = acc[mf][nf][r];
                    lsum += fmaxf(v + dc, 0.0f) + fmaxf(v + drow[mf][r], 0.0f);
                }
        }
    }
    for (int off = 32; off > 0; off >>= 1) lsum += __shfl_down(lsum, off, 64);

    __syncthreads();                     // LDS reuse for cross-wave reduce
    float* ws = (float*)sh;
    if (lane == 0) ws[w] = lsum;
    __syncthreads();
    if (tid == 0) {
        float s = 0.f;
#pragma unroll
        for (int i = 0; i < 8; ++i) s += ws[i];
        partials[blockIdx.x] = scale * s;
    }
}

// ---- final reduction --------------------------------------------------------
__global__ __launch_bounds__(256)
void reduce_kernel(const float* __restrict__ p, float* __restrict__ out) {
    const int t = threadIdx.x;
    float s = 0.f;
    for (int i = t; i < NBLK; i += 256) s += p[i];
    for (int off = 32; off > 0; off >>= 1) s += __shfl_down(s, off, 64);
    __shared__ float ws[4];
    if ((t & 63) == 0) ws[t >> 6] = s;
    __syncthreads();
    if (t == 0) out[0] = ws[0] + ws[1] + ws[2] + ws[3];
}

extern "C" void kernel_launch(void* const* d_in, const int* in_sizes, int n_in,
                              void* d_out, int out_size, void* d_ws, size_t ws_size,
                              hipStream_t stream) {
    // inputs: vgg(0) artist(1) genre(2) target_vgg(3) target_art(4) target_gen(5)
    const float* artist = (const float*)d_in[1];
    const float* genre  = (const float*)d_in[2];
    const float* tart   = (const float*)d_in[4];

    char* ws = (char*)d_ws;
    const size_t NE = (size_t)NROW * DDIM;
    unsigned short* artBf  = (unsigned short*)(ws);
    unsigned short* tartBf = (unsigned short*)(ws + NE * 2);
    unsigned short* genBf  = (unsigned short*)(ws + NE * 4);
    float* diagA    = (float*)(ws + NE * 6);
    float* diagG    = (float*)(ws + NE * 6 + NROW * 4);
    float* partials = (float*)(ws + NE * 6 + NROW * 8);

    prep_kernel<<<NROW, 256, 0, stream>>>(
        (const float4*)artist, (const float4*)tart, (const float4*)genre,
        (ushort4*)artBf, (ushort4*)tartBf, (ushort4*)genBf, diagA, diagG);

    hinge_gemm_kernel<<<NBLK, 512, 0, stream>>>(
        artBf, tartBf, genBf, diagA, diagG, partials);

    reduce_kernel<<<1, 256, 0, stream>>>(partials, (float*)d_out);
}

// Round 5
// 76.682 us; speedup vs baseline: 7.7649x; 7.7649x over previous
//
#include <hip/hip_runtime.h>

// PairwiseRankingLoss: out = 2*sum(cost_a) + sum(cost_g)
//   cost_x[i,j] = relu(score_x[i,j] + 0.2 - diag_x[j]) * (i != j)
//   score_a = artist @ target_art^T ; score_g = genre @ genre^T (symmetric)
// N=4096, D=1024. fp32 in; bf16 MFMA (2% rel threshold).
// Round 5: faithful m201-style 8-phase schedule. 256x256 tile, BK=64,
//   2 K-tiles per 8 phases, stage 1 half-tile per phase in read-retirement
//   order, vmcnt(6) once per K-tile (3 half-tiles in flight), ds_reads issued
//   pre-barrier, 7 barriers/K-tile, setprio around MFMA clusters.
//   launch_bounds(512,2) (round-4's (512,4) caused a 128-VGPR cap -> spill).

#define NROW 4096
#define DDIM 1024
#define MARGIN 0.2f
#define NT 16               // 4096 / 256 tiles per dim
#define NKT 16              // 1024 / 64 K-tiles
#define NBLK_ART 256        // 16*16 artist tiles
#define NBLK_GEN 136        // genre upper triangle incl. diagonal
#define NBLK (NBLK_ART + NBLK_GEN)   // 392 = 8*49

typedef __bf16 bf16x8 __attribute__((ext_vector_type(8)));
typedef float f32x4 __attribute__((ext_vector_type(4)));
typedef unsigned short ushort_t;

__device__ __forceinline__ unsigned short f2bf(float f) {
    unsigned int u = __builtin_bit_cast(unsigned int, f);
    u += 0x7fffu + ((u >> 16) & 1u);   // RNE
    return (unsigned short)(u >> 16);
}

__device__ __forceinline__ void gload_lds16(const void* g, void* l) {
    __builtin_amdgcn_global_load_lds(
        (const __attribute__((address_space(1))) void*)g,
        (__attribute__((address_space(3))) void*)l,
        16, 0, 0);
}

// ---- fused fp32->bf16 convert + per-row diagonals --------------------------
__global__ __launch_bounds__(256)
void prep_kernel(const float4* __restrict__ art, const float4* __restrict__ tart,
                 const float4* __restrict__ gen,
                 ushort4* __restrict__ artB, ushort4* __restrict__ tartB,
                 ushort4* __restrict__ genB,
                 float* __restrict__ diagA, float* __restrict__ diagG) {
    const int row = blockIdx.x;
    const int t = threadIdx.x;                  // 256 = DDIM/4 chunks
    const size_t idx = (size_t)row * (DDIM / 4) + t;
    float4 va = art[idx], vt = tart[idx], vg = gen[idx];
    ushort4 o;
    o.x = f2bf(va.x); o.y = f2bf(va.y); o.z = f2bf(va.z); o.w = f2bf(va.w); artB[idx] = o;
    o.x = f2bf(vt.x); o.y = f2bf(vt.y); o.z = f2bf(vt.z); o.w = f2bf(vt.w); tartB[idx] = o;
    o.x = f2bf(vg.x); o.y = f2bf(vg.y); o.z = f2bf(vg.z); o.w = f2bf(vg.w); genB[idx] = o;
    float pa = va.x * vt.x + va.y * vt.y + va.z * vt.z + va.w * vt.w;
    float pg = vg.x * vg.x + vg.y * vg.y + vg.z * vg.z + vg.w * vg.w;
    for (int off = 32; off > 0; off >>= 1) {
        pa += __shfl_down(pa, off, 64);
        pg += __shfl_down(pg, off, 64);
    }
    __shared__ float sA[4], sG[4];
    if ((t & 63) == 0) { sA[t >> 6] = pa; sG[t >> 6] = pg; }
    __syncthreads();
    if (t == 0) {
        diagA[row] = sA[0] + sA[1] + sA[2] + sA[3];
        diagG[row] = sG[0] + sG[1] + sG[2] + sG[3];
    }
}

// ---- LDS geometry (ushort units, 65536 total = 128 KiB) ---------------------
// A buf b: [b*16384, +16384); B buf b: [32768 + b*16384, +16384).
// A region(mh): +mh*8192, two 64-row bands (waveM): +waveM*4096,
//   local row lr (0..63): +lr*64, slot s (0..7, 16B each): +s*8.
// B region(nh): +nh*8192, four 32-row bands (waveN): +waveN*2048,
//   local row lr (0..31): +lr*64, slot s: +s*8.
// Swizzle: LDS slot s holds global k-group s ^ (lr&7)  [involution, both sides].
// Half-tile H: tile T = H>>2, kind = H&3 in order [A0, B0, B1, A1].
// Stage at global phase P (= 4*T + p-1) targets H = P + 7:
//   tile T: P1 -> A1 of T+1; P2 -> A0 of T+2; P3 -> B0 of T+2; P4 -> B1 of T+2.
// Each target region's last ds_read closed >=1 phase before the stage issues.
// vmcnt(6) at each tile's P4 protects tile T+1 (3 half-tiles in flight).

__device__ __forceinline__
void stage_half(int H, const ushort_t* __restrict__ Ablk,
                const ushort_t* __restrict__ Bblk, ushort_t* sh, int tid) {
    if (H >= NKT * 4) return;
    const int T = H >> 2, kind = H & 3, buf = T & 1, kt = T << 6;
    if (kind == 0 || kind == 3) {                 // A0 / A1
        const int half = (kind == 3);
        ushort_t* dst = sh + buf * 16384 + half * 8192;
#pragma unroll
        for (int i = 0; i < 2; ++i) {
            const int q = i * 512 + tid;          // 16B chunk 0..1023
            const int band = q >> 9, lr = (q >> 3) & 63, slot = q & 7;
            const int row = band * 128 + half * 64 + lr;
            const int gk = slot ^ (lr & 7);
            gload_lds16(Ablk + (size_t)row * DDIM + kt + gk * 8, dst + q * 8);
        }
    } else {                                      // B0 (kind=1) / B1 (kind=2)
        const int half = (kind == 2);
        ushort_t* dst = sh + 32768 + buf * 16384 + half * 8192;
#pragma unroll
        for (int i = 0; i < 2; ++i) {
            const int q = i * 512 + tid;
            const int band = q >> 8, lr = (q >> 3) & 31, slot = q & 7;
            const int row = band * 64 + half * 32 + lr;
            const int gk = slot ^ (lr & 7);
            gload_lds16(Bblk + (size_t)row * DDIM + kt + gk * 8, dst + q * 8);
        }
    }
}

__device__ __forceinline__
void dsloadA(bf16x8 aF[2][4], const ushort_t* lA, int mh, int waveM, int lane) {
    const int l15 = lane & 15;
    const int kg = lane >> 4;
    const ushort_t* base = lA + mh * 8192 + waveM * 4096 + l15 * 64;
#pragma unroll
    for (int kh = 0; kh < 2; ++kh)
#pragma unroll
        for (int m = 0; m < 4; ++m)
            aF[kh][m] = *(const bf16x8*)&base[m * 1024 + ((((kh << 2) + kg) ^ (l15 & 7)) << 3)];
}

__device__ __forceinline__
void dsloadB(bf16x8 bF[2][2], const ushort_t* lB, int nh, int waveN, int lane) {
    const int l15 = lane & 15;
    const int kg = lane >> 4;
    const ushort_t* base = lB + nh * 8192 + waveN * 2048 + l15 * 64;
#pragma unroll
    for (int kh = 0; kh < 2; ++kh)
#pragma unroll
        for (int n = 0; n < 2; ++n)
            bF[kh][n] = *(const bf16x8*)&base[n * 1024 + ((((kh << 2) + kg) ^ (l15 & 7)) << 3)];
}

template <int MH, int NH>
__device__ __forceinline__
void mfmaQuad(f32x4 acc[8][4], const bf16x8 aF[2][4], const bf16x8 bF[2][2]) {
#pragma unroll
    for (int kh = 0; kh < 2; ++kh)
#pragma unroll
        for (int m = 0; m < 4; ++m)
#pragma unroll
            for (int n = 0; n < 2; ++n)
                acc[MH * 4 + m][NH * 2 + n] = __builtin_amdgcn_mfma_f32_16x16x32_bf16(
                    aF[kh][m], bF[kh][n], acc[MH * 4 + m][NH * 2 + n], 0, 0, 0);
}

#define WAIT_LGKM0() do { \
    asm volatile("s_waitcnt lgkmcnt(0)" ::: "memory"); \
    __builtin_amdgcn_sched_barrier(0); } while (0)

// ---- fused 256x256 GEMM + hinge + reduction ---------------------------------
__global__ __launch_bounds__(512, 2)
void hinge_gemm_kernel(const ushort_t* __restrict__ artB,
                       const ushort_t* __restrict__ tartB,
                       const ushort_t* __restrict__ genB,
                       const float* __restrict__ diagA,
                       const float* __restrict__ diagG,
                       float* __restrict__ partials) {
    __shared__ ushort_t sh[65536];   // 128 KiB

    // bijective XCD swizzle: 392 = 8 * 49
    const int bid = ((int)blockIdx.x & 7) * 49 + ((int)blockIdx.x >> 3);

    const ushort_t* A;
    const ushort_t* B;
    const float* dg;
    int tr, tc, mode;          // mode 0: single hinge + diag mask; 1: dual hinge
    float scale;
    if (bid < NBLK_ART) {
        A = artB; B = tartB; dg = diagA; scale = 2.0f;
        tr = bid >> 4; tc = bid & 15; mode = 0;
    } else {
        int u = bid - NBLK_ART;
        int r = 0;
        while (u >= NT - r) { u -= NT - r; ++r; }
        tr = r; tc = r + u;
        A = genB; B = genB; dg = diagG; scale = 1.0f;
        mode = (tr == tc) ? 0 : 1;
    }

    const int tid = threadIdx.x;
    const int w = tid >> 6;
    const int lane = tid & 63;
    const int waveM = w >> 2;        // 2 wave-rows (128 rows each)
    const int waveN = w & 3;         // 4 wave-cols (64 cols each)

    const ushort_t* Ablk = A + (size_t)tr * 256 * DDIM;
    const ushort_t* Bblk = B + (size_t)tc * 256 * DDIM;

    f32x4 acc[8][4];
#pragma unroll
    for (int m = 0; m < 8; ++m)
#pragma unroll
        for (int n = 0; n < 4; ++n)
            acc[m][n] = (f32x4){0.f, 0.f, 0.f, 0.f};

    bf16x8 aF[2][4];          // current mh's A frags (reused A0 -> A1)
    bf16x8 bF0[2][2], bF1[2][2];

    // prologue: halves 0..6 (tile0 full + tile1 A0,B0,B1); tile1 A1 staged at P1.
#pragma unroll
    for (int H = 0; H < 7; ++H) stage_half(H, Ablk, Bblk, sh, tid);
    asm volatile("s_waitcnt vmcnt(6)" ::: "memory");   // tile0 landed
    __builtin_amdgcn_sched_barrier(0);
    __builtin_amdgcn_s_barrier();

#pragma unroll 1
    for (int T = 0; T < NKT; ++T) {
        const ushort_t* lA = sh + (T & 1) * 16384;
        const ushort_t* lB = sh + 32768 + (T & 1) * 16384;
        const int Pb = T * 4;

        // ---- P1: dsload A0 (8) + B0 (4); stage A1 of T+1; MFMA q(0,0) ----
        dsloadA(aF, lA, 0, waveM, lane);
        dsloadB(bF0, lB, 0, waveN, lane);
        stage_half(Pb + 7, Ablk, Bblk, sh, tid);
        asm volatile("s_waitcnt lgkmcnt(8)" ::: "memory");  // bound ds queue
        __builtin_amdgcn_s_barrier();
        WAIT_LGKM0();
        __builtin_amdgcn_s_setprio(1);
        mfmaQuad<0, 0>(acc, aF, bF0);
        __builtin_amdgcn_s_setprio(0);
        __builtin_amdgcn_s_barrier();

        // ---- P2: dsload B1 (4); stage A0 of T+2; MFMA q(0,1) ----
        dsloadB(bF1, lB, 1, waveN, lane);
        stage_half(Pb + 8, Ablk, Bblk, sh, tid);
        __builtin_amdgcn_s_barrier();
        WAIT_LGKM0();
        __builtin_amdgcn_s_setprio(1);
        mfmaQuad<0, 1>(acc, aF, bF1);
        __builtin_amdgcn_s_setprio(0);
        __builtin_amdgcn_s_barrier();

        // ---- P3: dsload A1 (8); stage B0 of T+2; MFMA q(1,0) ----
        dsloadA(aF, lA, 1, waveM, lane);
        stage_half(Pb + 9, Ablk, Bblk, sh, tid);
        __builtin_amdgcn_s_barrier();
        WAIT_LGKM0();
        __builtin_amdgcn_s_setprio(1);
        mfmaQuad<1, 0>(acc, aF, bF0);
        __builtin_amdgcn_s_setprio(0);
        __builtin_amdgcn_s_barrier();

        // ---- P4: stage B1 of T+2; MFMA q(1,1); vmcnt protects tile T+1 ----
        stage_half(Pb + 10, Ablk, Bblk, sh, tid);
        __builtin_amdgcn_s_setprio(1);
        mfmaQuad<1, 1>(acc, aF, bF1);
        __builtin_amdgcn_s_setprio(0);
        if (T < NKT - 2)       asm volatile("s_waitcnt vmcnt(6)" ::: "memory");
        else if (T == NKT - 2) asm volatile("s_waitcnt vmcnt(0)" ::: "memory");
        __builtin_amdgcn_s_barrier();
    }

    // ---- epilogue: hinge + reduction ----
    // C/D layout: col = lane&15, row = (lane>>4)*4 + reg
    const int rowBase = tr * 256 + waveM * 128 + ((lane >> 4) << 2);
    const int colBase = tc * 256 + waveN * 64 + (lane & 15);
    float lsum = 0.0f;
    if (mode == 0) {
#pragma unroll
        for (int nf = 0; nf < 4; ++nf) {
            const int gcol = colBase + nf * 16;
            const float dc = MARGIN - dg[gcol];
#pragma unroll
            for (int mf = 0; mf < 8; ++mf) {
                const int grow0 = rowBase + mf * 16;
#pragma unroll
                for (int r = 0; r < 4; ++r) {
                    float v = fmaxf(acc[mf][nf][r] + dc, 0.0f);
                    if (grow0 + r == gcol) v = 0.0f;
                    lsum += v;
                }
            }
        }
    } else {
        // strictly-above-diagonal genre tile: v = g[i,j] = g[j,i] contributes
        // relu(v + c_j) [this tile] + relu(v + c_i) [mirror tile]
        float drow[8][4];
#pragma unroll
        for (int mf = 0; mf < 8; ++mf)
#pragma unroll
            for (int r = 0; r < 4; ++r)
                drow[mf][r] = MARGIN - dg[rowBase + mf * 16 + r];
#pragma unroll
        for (int nf = 0; nf < 4; ++nf) {
            const float dc = MARGIN - dg[colBase + nf * 16];
#pragma unroll
            for (int mf = 0; mf < 8; ++mf)
#pragma unroll
                for (int r = 0; r < 4; ++r) {
                    const float v = acc[mf][nf][r];
                    lsum += fmaxf(v + dc, 0.0f) + fmaxf(v + drow[mf][r], 0.0f);
                }
        }
    }
    for (int off = 32; off > 0; off >>= 1) lsum += __shfl_down(lsum, off, 64);

    __syncthreads();                     // LDS reuse for cross-wave reduce
    float* ws = (float*)sh;
    if (lane == 0) ws[w] = lsum;
    __syncthreads();
    if (tid == 0) {
        float s = 0.f;
#pragma unroll
        for (int i = 0; i < 8; ++i) s += ws[i];
        partials[blockIdx.x] = scale * s;
    }
}

// ---- final reduction --------------------------------------------------------
__global__ __launch_bounds__(256)
void reduce_kernel(const float* __restrict__ p, float* __restrict__ out) {
    const int t = threadIdx.x;
    float s = 0.f;
    for (int i = t; i < NBLK; i += 256) s += p[i];
    for (int off = 32; off > 0; off >>= 1) s += __shfl_down(s, off, 64);
    __shared__ float ws[4];
    if ((t & 63) == 0) ws[t >> 6] = s;
    __syncthreads();
    if (t == 0) out[0] = ws[0] + ws[1] + ws[2] + ws[3];
}

extern "C" void kernel_launch(void* const* d_in, const int* in_sizes, int n_in,
                              void* d_out, int out_size, void* d_ws, size_t ws_size,
                              hipStream_t stream) {
    // inputs: vgg(0) artist(1) genre(2) target_vgg(3) target_art(4) target_gen(5)
    const float* artist = (const float*)d_in[1];
    const float* genre  = (const float*)d_in[2];
    const float* tart   = (const float*)d_in[4];

    char* ws = (char*)d_ws;
    const size_t NE = (size_t)NROW * DDIM;
    unsigned short* artBf  = (unsigned short*)(ws);
    unsigned short* tartBf = (unsigned short*)(ws + NE * 2);
    unsigned short* genBf  = (unsigned short*)(ws + NE * 4);
    float* diagA    = (float*)(ws + NE * 6);
    float* diagG    = (float*)(ws + NE * 6 + NROW * 4);
    float* partials = (float*)(ws + NE * 6 + NROW * 8);

    prep_kernel<<<NROW, 256, 0, stream>>>(
        (const float4*)artist, (const float4*)tart, (const float4*)genre,
        (ushort4*)artBf, (ushort4*)tartBf, (ushort4*)genBf, diagA, diagG);

    hinge_gemm_kernel<<<NBLK, 512, 0, stream>>>(
        artBf, tartBf, genBf, diagA, diagG, partials);

    reduce_kernel<<<1, 256, 0, stream>>>(partials, (float*)d_out);
}

// Round 6
// 54.103 us; speedup vs baseline: 11.0055x; 1.4173x over previous
//
#include <hip/hip_runtime.h>

// PairwiseRankingLoss: out = 2*sum(cost_a) + sum(cost_g)
//   cost_x[i,j] = relu(score_x[i,j] + 0.2 - diag_x[j]) * (i != j)
//   score_a = artist @ target_art^T ; score_g = genre @ genre^T (symmetric)
// N=4096, D=1024. fp32 in; scores via MX-fp8 (e4m3, scales=1.0) MFMA
// mfma_scale_f32_16x16x128_f8f6f4 (2x bf16 rate, half the staging bytes).
// Round 6: round-5's verified 4-phase/K-tile schedule, dtype bf16 -> fp8.
//   256x256 tile, BK=128, NKT=8, 8 waves, 128 KiB LDS dbuf, vmcnt(6),
//   3-bit XOR swizzle (8 slots/128B row), diag kept fp32.

#define NROW 4096
#define DDIM 1024
#define MARGIN 0.2f
#define NT 16               // 4096 / 256 tiles per dim
#define NKT 8               // 1024 / 128 K-tiles
#define NBLK_ART 256        // 16*16 artist tiles
#define NBLK_GEN 136        // genre upper triangle incl. diagonal
#define NBLK (NBLK_ART + NBLK_GEN)   // 392 = 8*49

typedef float f32x4 __attribute__((ext_vector_type(4)));
typedef int i32x8 __attribute__((ext_vector_type(8)));
typedef unsigned char uchar_t;

#define SCALE_ONE 0x7F7F7F7F   // E8M0 127 = 2^0 in every byte

__device__ __forceinline__ void gload_lds16(const void* g, void* l) {
    __builtin_amdgcn_global_load_lds(
        (const __attribute__((address_space(1))) void*)g,
        (__attribute__((address_space(3))) void*)l,
        16, 0, 0);
}

// ---- fused fp32 -> fp8(e4m3) convert + per-row fp32 diagonals ---------------
__global__ __launch_bounds__(256)
void prep_kernel(const float4* __restrict__ art, const float4* __restrict__ tart,
                 const float4* __restrict__ gen,
                 unsigned int* __restrict__ artP, unsigned int* __restrict__ tartP,
                 unsigned int* __restrict__ genP,
                 float* __restrict__ diagA, float* __restrict__ diagG) {
    const int row = blockIdx.x;
    const int t = threadIdx.x;                  // 256 = DDIM/4 chunks
    const size_t idx = (size_t)row * (DDIM / 4) + t;
    float4 va = art[idx], vt = tart[idx], vg = gen[idx];
    unsigned int pk;
    pk = (unsigned int)__builtin_amdgcn_cvt_pk_fp8_f32(va.x, va.y, 0, false);
    pk = (unsigned int)__builtin_amdgcn_cvt_pk_fp8_f32(va.z, va.w, (int)pk, true);
    artP[idx] = pk;
    pk = (unsigned int)__builtin_amdgcn_cvt_pk_fp8_f32(vt.x, vt.y, 0, false);
    pk = (unsigned int)__builtin_amdgcn_cvt_pk_fp8_f32(vt.z, vt.w, (int)pk, true);
    tartP[idx] = pk;
    pk = (unsigned int)__builtin_amdgcn_cvt_pk_fp8_f32(vg.x, vg.y, 0, false);
    pk = (unsigned int)__builtin_amdgcn_cvt_pk_fp8_f32(vg.z, vg.w, (int)pk, true);
    genP[idx] = pk;
    float pa = va.x * vt.x + va.y * vt.y + va.z * vt.z + va.w * vt.w;
    float pg = vg.x * vg.x + vg.y * vg.y + vg.z * vg.z + vg.w * vg.w;
    for (int off = 32; off > 0; off >>= 1) {
        pa += __shfl_down(pa, off, 64);
        pg += __shfl_down(pg, off, 64);
    }
    __shared__ float sA[4], sG[4];
    if ((t & 63) == 0) { sA[t >> 6] = pa; sG[t >> 6] = pg; }
    __syncthreads();
    if (t == 0) {
        diagA[row] = sA[0] + sA[1] + sA[2] + sA[3];
        diagG[row] = sG[0] + sG[1] + sG[2] + sG[3];
    }
}

// ---- LDS geometry (bytes, 131072 total = 128 KiB) ---------------------------
// A buf b: [b*32768); region mh: +mh*16384: [band(2)][lr(64)][128B row].
//   global A row = band*128 + mh*64 + lr.
// B buf b: 65536 + b*32768; region nh: +nh*16384: [band(4)][lr(32)][128B].
//   global B row = band*64 + nh*32 + lr.
// Row = 128 fp8 = 8 slots of 16B. Swizzle: LDS slot s holds global k-group
//   s ^ (lr&7)  [3-bit involution, applied on source and on read].
// Half-tile H: tile T = H>>2, kind = H&3 in order [A0, B0, B1, A1].
// Stage at tile T: P1 -> A1 of T+1; P2 -> A0 of T+2; P3 -> B0 of T+2;
//   P4 -> B1 of T+2. vmcnt(6) at P4 protects tile T+1 (3 halves in flight).

__device__ __forceinline__
void stage_half(int H, const uchar_t* __restrict__ Ablk,
                const uchar_t* __restrict__ Bblk, uchar_t* sh, int tid) {
    if (H >= NKT * 4) return;
    const int T = H >> 2, kind = H & 3, buf = T & 1;
    const int kt = T << 7;                        // byte offset along K
    if (kind == 0 || kind == 3) {                 // A0 / A1
        const int mh = (kind == 3);
        uchar_t* dst = sh + buf * 32768 + mh * 16384;
#pragma unroll
        for (int i = 0; i < 2; ++i) {
            const int q = i * 512 + tid;          // 16B chunk 0..1023
            const int slot = q & 7, lr = (q >> 3) & 63, band = q >> 9;
            const int row = band * 128 + mh * 64 + lr;
            const int gk = slot ^ (lr & 7);
            gload_lds16(Ablk + (size_t)row * DDIM + kt + gk * 16, dst + q * 16);
        }
    } else {                                      // B0 (kind=1) / B1 (kind=2)
        const int nh = (kind == 2);
        uchar_t* dst = sh + 65536 + buf * 32768 + nh * 16384;
#pragma unroll
        for (int i = 0; i < 2; ++i) {
            const int q = i * 512 + tid;
            const int slot = q & 7, lr = (q >> 3) & 31, band = q >> 8;
            const int row = band * 64 + nh * 32 + lr;
            const int gk = slot ^ (lr & 7);
            gload_lds16(Bblk + (size_t)row * DDIM + kt + gk * 16, dst + q * 16);
        }
    }
}

// A fragment (16x128, lane l: row=l&15, k-bytes (l>>4)*32..+31): 2 x b128.
__device__ __forceinline__
void dsloadA(i32x8 aF[4], const uchar_t* lA, int mh, int waveM, int lane) {
    const int l15 = lane & 15, kg = lane >> 4, r7 = l15 & 7;
    const uchar_t* base = lA + mh * 16384 + waveM * 8192 + l15 * 128;
    const int s0 = ((2 * kg) ^ r7) << 4;
    const int s1 = ((2 * kg + 1) ^ r7) << 4;
#pragma unroll
    for (int m = 0; m < 4; ++m) {
        const uchar_t* p = base + m * 2048;       // +16 rows
        int4 lo = *(const int4*)(p + s0);
        int4 hi = *(const int4*)(p + s1);
        i32x8 v;
        v[0] = lo.x; v[1] = lo.y; v[2] = lo.z; v[3] = lo.w;
        v[4] = hi.x; v[5] = hi.y; v[6] = hi.z; v[7] = hi.w;
        aF[m] = v;
    }
}

__device__ __forceinline__
void dsloadB(i32x8 bF[2], const uchar_t* lB, int nh, int waveN, int lane) {
    const int l15 = lane & 15, kg = lane >> 4, r7 = l15 & 7;
    const uchar_t* base = lB + nh * 16384 + waveN * 4096 + l15 * 128;
    const int s0 = ((2 * kg) ^ r7) << 4;
    const int s1 = ((2 * kg + 1) ^ r7) << 4;
#pragma unroll
    for (int n = 0; n < 2; ++n) {
        const uchar_t* p = base + n * 2048;
        int4 lo = *(const int4*)(p + s0);
        int4 hi = *(const int4*)(p + s1);
        i32x8 v;
        v[0] = lo.x; v[1] = lo.y; v[2] = lo.z; v[3] = lo.w;
        v[4] = hi.x; v[5] = hi.y; v[6] = hi.z; v[7] = hi.w;
        bF[n] = v;
    }
}

template <int MH, int NH>
__device__ __forceinline__
void mfmaQuad(f32x4 acc[8][4], const i32x8 aF[4], const i32x8 bF[2]) {
#pragma unroll
    for (int m = 0; m < 4; ++m)
#pragma unroll
        for (int n = 0; n < 2; ++n)
            acc[MH * 4 + m][NH * 2 + n] =
                __builtin_amdgcn_mfma_scale_f32_16x16x128_f8f6f4(
                    aF[m], bF[n], acc[MH * 4 + m][NH * 2 + n],
                    0, 0,                      // cbsz=fp8, blgp=fp8
                    0, SCALE_ONE,              // opsel_a, scale_a (all 1.0)
                    0, SCALE_ONE);             // opsel_b, scale_b
}

#define WAIT_LGKM0() do { \
    asm volatile("s_waitcnt lgkmcnt(0)" ::: "memory"); \
    __builtin_amdgcn_sched_barrier(0); } while (0)

// ---- fused 256x256 GEMM + hinge + reduction ---------------------------------
__global__ __launch_bounds__(512, 2)
void hinge_gemm_kernel(const uchar_t* __restrict__ artP,
                       const uchar_t* __restrict__ tartP,
                       const uchar_t* __restrict__ genP,
                       const float* __restrict__ diagA,
                       const float* __restrict__ diagG,
                       float* __restrict__ partials) {
    __shared__ uchar_t sh[131072];   // 128 KiB

    // bijective XCD swizzle: 392 = 8 * 49
    const int bid = ((int)blockIdx.x & 7) * 49 + ((int)blockIdx.x >> 3);

    const uchar_t* A;
    const uchar_t* B;
    const float* dg;
    int tr, tc, mode;          // mode 0: single hinge + diag mask; 1: dual hinge
    float scale;
    if (bid < NBLK_ART) {
        A = artP; B = tartP; dg = diagA; scale = 2.0f;
        tr = bid >> 4; tc = bid & 15; mode = 0;
    } else {
        int u = bid - NBLK_ART;
        int r = 0;
        while (u >= NT - r) { u -= NT - r; ++r; }
        tr = r; tc = r + u;
        A = genP; B = genP; dg = diagG; scale = 1.0f;
        mode = (tr == tc) ? 0 : 1;
    }

    const int tid = threadIdx.x;
    const int w = tid >> 6;
    const int lane = tid & 63;
    const int waveM = w >> 2;        // 2 wave-rows (128 rows each)
    const int waveN = w & 3;         // 4 wave-cols (64 cols each)

    const uchar_t* Ablk = A + (size_t)tr * 256 * DDIM;
    const uchar_t* Bblk = B + (size_t)tc * 256 * DDIM;

    f32x4 acc[8][4];
#pragma unroll
    for (int m = 0; m < 8; ++m)
#pragma unroll
        for (int n = 0; n < 4; ++n)
            acc[m][n] = (f32x4){0.f, 0.f, 0.f, 0.f};

    i32x8 aF[4];              // current mh's A frags (reused A0 -> A1)
    i32x8 bF0[2], bF1[2];

    // prologue: halves 0..6 (tile0 full + tile1 A0,B0,B1); tile1 A1 at P1.
#pragma unroll
    for (int H = 0; H < 7; ++H) stage_half(H, Ablk, Bblk, sh, tid);
    asm volatile("s_waitcnt vmcnt(6)" ::: "memory");   // tile0 landed
    __builtin_amdgcn_sched_barrier(0);
    __builtin_amdgcn_s_barrier();

#pragma unroll 1
    for (int T = 0; T < NKT; ++T) {
        const uchar_t* lA = sh + (T & 1) * 32768;
        const uchar_t* lB = sh + 65536 + (T & 1) * 32768;
        const int Pb = T * 4;

        // ---- P1: dsload A0 (8 b128) + B0 (4); stage A1 of T+1; MFMA q(0,0) --
        dsloadA(aF, lA, 0, waveM, lane);
        dsloadB(bF0, lB, 0, waveN, lane);
        stage_half(Pb + 7, Ablk, Bblk, sh, tid);
        asm volatile("s_waitcnt lgkmcnt(8)" ::: "memory");  // bound ds queue
        __builtin_amdgcn_s_barrier();
        WAIT_LGKM0();
        __builtin_amdgcn_s_setprio(1);
        mfmaQuad<0, 0>(acc, aF, bF0);
        __builtin_amdgcn_s_setprio(0);
        __builtin_amdgcn_s_barrier();

        // ---- P2: dsload B1 (4); stage A0 of T+2; MFMA q(0,1) ----
        dsloadB(bF1, lB, 1, waveN, lane);
        stage_half(Pb + 8, Ablk, Bblk, sh, tid);
        __builtin_amdgcn_s_barrier();
        WAIT_LGKM0();
        __builtin_amdgcn_s_setprio(1);
        mfmaQuad<0, 1>(acc, aF, bF1);
        __builtin_amdgcn_s_setprio(0);
        __builtin_amdgcn_s_barrier();

        // ---- P3: dsload A1 (8); stage B0 of T+2; MFMA q(1,0) ----
        dsloadA(aF, lA, 1, waveM, lane);
        stage_half(Pb + 9, Ablk, Bblk, sh, tid);
        __builtin_amdgcn_s_barrier();
        WAIT_LGKM0();
        __builtin_amdgcn_s_setprio(1);
        mfmaQuad<1, 0>(acc, aF, bF0);
        __builtin_amdgcn_s_setprio(0);
        __builtin_amdgcn_s_barrier();

        // ---- P4: stage B1 of T+2; MFMA q(1,1); vmcnt protects tile T+1 ----
        stage_half(Pb + 10, Ablk, Bblk, sh, tid);
        __builtin_amdgcn_s_setprio(1);
        mfmaQuad<1, 1>(acc, aF, bF1);
        __builtin_amdgcn_s_setprio(0);
        if (T < NKT - 2)       asm volatile("s_waitcnt vmcnt(6)" ::: "memory");
        else if (T == NKT - 2) asm volatile("s_waitcnt vmcnt(0)" ::: "memory");
        __builtin_amdgcn_s_barrier();
    }

    // ---- epilogue: hinge + reduction ----
    // C/D layout (shape-determined): col = lane&15, row = (lane>>4)*4 + reg
    const int rowBase = tr * 256 + waveM * 128 + ((lane >> 4) << 2);
    const int colBase = tc * 256 + waveN * 64 + (lane & 15);
    float lsum = 0.0f;
    if (mode == 0) {
#pragma unroll
        for (int nf = 0; nf < 4; ++nf) {
            const int gcol = colBase + nf * 16;
            const float dc = MARGIN - dg[gcol];
#pragma unroll
            for (int mf = 0; mf < 8; ++mf) {
                const int grow0 = rowBase + mf * 16;
#pragma unroll
                for (int r = 0; r < 4; ++r) {
                    float v = fmaxf(acc[mf][nf][r] + dc, 0.0f);
                    if (grow0 + r == gcol) v = 0.0f;
                    lsum += v;
                }
            }
        }
    } else {
        // strictly-above-diagonal genre tile: v = g[i,j] = g[j,i] contributes
        // relu(v + c_j) [this tile] + relu(v + c_i) [mirror tile]
        float drow[8][4];
#pragma unroll
        for (int mf = 0; mf < 8; ++mf)
#pragma unroll
            for (int r = 0; r < 4; ++r)
                drow[mf][r] = MARGIN - dg[rowBase + mf * 16 + r];
#pragma unroll
        for (int nf = 0; nf < 4; ++nf) {
            const float dc = MARGIN - dg[colBase + nf * 16];
#pragma unroll
            for (int mf = 0; mf < 8; ++mf)
#pragma unroll
                for (int r = 0; r < 4; ++r) {
                    const float v = acc[mf][nf][r];
                    lsum += fmaxf(v + dc, 0.0f) + fmaxf(v + drow[mf][r], 0.0f);
                }
        }
    }
    for (int off = 32; off > 0; off >>= 1) lsum += __shfl_down(lsum, off, 64);

    __syncthreads();                     // LDS reuse for cross-wave reduce
    float* ws = (float*)sh;
    if (lane == 0) ws[w] = lsum;
    __syncthreads();
    if (tid == 0) {
        float s = 0.f;
#pragma unroll
        for (int i = 0; i < 8; ++i) s += ws[i];
        partials[blockIdx.x] = scale * s;
    }
}

// ---- final reduction --------------------------------------------------------
__global__ __launch_bounds__(256)
void reduce_kernel(const float* __restrict__ p, float* __restrict__ out) {
    const int t = threadIdx.x;
    float s = 0.f;
    for (int i = t; i < NBLK; i += 256) s += p[i];
    for (int off = 32; off > 0; off >>= 1) s += __shfl_down(s, off, 64);
    __shared__ float ws[4];
    if ((t & 63) == 0) ws[t >> 6] = s;
    __syncthreads();
    if (t == 0) out[0] = ws[0] + ws[1] + ws[2] + ws[3];
}

extern "C" void kernel_launch(void* const* d_in, const int* in_sizes, int n_in,
                              void* d_out, int out_size, void* d_ws, size_t ws_size,
                              hipStream_t stream) {
    // inputs: vgg(0) artist(1) genre(2) target_vgg(3) target_art(4) target_gen(5)
    const float* artist = (const float*)d_in[1];
    const float* genre  = (const float*)d_in[2];
    const float* tart   = (const float*)d_in[4];

    char* ws = (char*)d_ws;
    const size_t NE = (size_t)NROW * DDIM;      // elements; fp8 = 1 B each
    uchar_t* artF8  = (uchar_t*)(ws);
    uchar_t* tartF8 = (uchar_t*)(ws + NE);
    uchar_t* genF8  = (uchar_t*)(ws + NE * 2);
    float* diagA    = (float*)(ws + NE * 3);
    float* diagG    = (float*)(ws + NE * 3 + NROW * 4);
    float* partials = (float*)(ws + NE * 3 + NROW * 8);

    prep_kernel<<<NROW, 256, 0, stream>>>(
        (const float4*)artist, (const float4*)tart, (const float4*)genre,
        (unsigned int*)artF8, (unsigned int*)tartF8, (unsigned int*)genF8,
        diagA, diagG);

    hinge_gemm_kernel<<<NBLK, 512, 0, stream>>>(
        artF8, tartF8, genF8, diagA, diagG, partials);

    reduce_kernel<<<1, 256, 0, stream>>>(partials, (float*)d_out);
}